// Round 18
// baseline (78.804 us; speedup 1.0000x reference)
//
#include <hip/hip_runtime.h>

// SSIM loss, fused separable Gaussian (11x11, sigma=1.5) over [32,3,512,512] f32.
// R18 = R17 + V-load asm liveness anchor (single-variable change):
//   R17 counters show VGPR_Count=32 while the V-phase holds 36 loaded values
//   (pv[18]+tv[18]) -> the compiler STILL serializes the load batch into
//   load->wait->use chains (sched_barrier(0) pins the scheduler, not the RA).
//   One asm volatile consuming all 36 values as "v" operands forces them
//   simultaneously live -> loads must batch -> one exposed VMEM latency per
//   V-phase. (R9 proved the anchor forces the allocation; its dur effect was
//   masked then by the atomic wall removed in R11.)
// Kept from R17: 512-thread blocks (8 waves), 8x256 tile, V on tid<266,
// H on all 512 (one row-quad each), XCD-bijective swizzle, pk f32x2 chains,
// linear stats LDS, plain store + reduce kernel.

typedef float f32x2 __attribute__((ext_vector_type(2)));

#define IH 512
#define IW 512
#define TH 8                 // output rows per tile
#define TW 256               // output cols per tile
#define PW 266               // TW + 10 FIR cols
#define RRN 18               // raw rows per tile
#define LPW 268              // stats row stride in f32x2
#define HTILES 64
#define NBLK 12288           // 96 images * 64 ht * 2 wt
#define CPX 1536             // NBLK / 8 XCDs (exact -> bijective)
#define NPIX 25165824.0f     // 96*512*512
#define NTHR 512

constexpr float GW[11] = {
    0.00102838f, 0.00759877f, 0.03600078f, 0.10936070f, 0.21300554f,
    0.26601173f,
    0.21300554f, 0.10936070f, 0.03600078f, 0.00759877f, 0.00102838f
};
constexpr float C1f = 0.0001f;  // 0.01^2
constexpr float C2f = 0.0009f;  // 0.03^2

__global__ __launch_bounds__(1024) void ssim_reduce(
    const float* __restrict__ ws, float* __restrict__ out)
{
    __shared__ float wsum[16];
    const int tid = threadIdx.x;
    const float4* w4 = reinterpret_cast<const float4*>(ws);  // 3072 float4
    float s = 0.0f;
    #pragma unroll
    for (int i = 0; i < 3; ++i) {
        const float4 v = w4[tid + i * 1024];
        s += (v.x + v.y) + (v.z + v.w);
    }
    #pragma unroll
    for (int off = 32; off > 0; off >>= 1) s += __shfl_down(s, off, 64);
    if ((tid & 63) == 0) wsum[tid >> 6] = s;
    __syncthreads();
    if (tid == 0) {
        float t = 0.f;
        #pragma unroll
        for (int i = 0; i < 16; ++i) t += wsum[i];
        out[0] = 1.0f - t * (1.0f / NPIX);
    }
}

__global__ __launch_bounds__(NTHR, 8) void ssim_main(
    const float* __restrict__ pred,
    const float* __restrict__ targ,
    float* __restrict__ ws)
{
    __shared__ __align__(16) f32x2 lds01[TH][LPW];   // (E[p], E[t])
    __shared__ __align__(16) f32x2 lds23[TH][LPW];   // (E[p^2+t^2], E[p*t])
    __shared__ float wsum[8];

    const int tid = threadIdx.x;

    // -------- XCD-bijective swizzle: tl-consecutive tiles share an XCD -----
    const int b  = blockIdx.x;
    const int tl = (b & 7) * CPX + (b >> 3);
    const int ht = tl & (HTILES - 1);            // consecutive ht share rows
    const int wt = (tl >> 6) & 1;
    const int bc = tl >> 7;

    const int rbase = ht * TH - 5;
    const bool vint = (ht != 0) && (ht != HTILES - 1);   // uniform
    const float* __restrict__ P = pred + (size_t)bc * (IH * IW);
    const float* __restrict__ T = targ + (size_t)bc * (IH * IW);

    // ---------------- V-phase: 18-row column FIR (tid < 266) ---------------
    if (tid < PW) {
        const int w = wt * TW - 5 + tid;
        const float wm = ((unsigned)w < (unsigned)IW) ? 1.0f : 0.0f;
        const int wc = w < 0 ? 0 : (w > IW - 1 ? IW - 1 : w);

        float pv[RRN], tv[RRN];
        if (vint) {
            // interior: no clamps, no masks
            const float* __restrict__ Pp = P + (size_t)rbase * IW + wc;
            const float* __restrict__ Tp = T + (size_t)rbase * IW + wc;
            #pragma unroll
            for (int rr = 0; rr < RRN; ++rr) pv[rr] = Pp[(size_t)rr * IW];
            #pragma unroll
            for (int rr = 0; rr < RRN; ++rr) tv[rr] = Tp[(size_t)rr * IW];
        } else {
            // border: clamp rows + zero masks
            #pragma unroll
            for (int rr = 0; rr < RRN; ++rr) {
                const int h = rbase + rr;
                const int hc = h < 0 ? 0 : (h > IH - 1 ? IH - 1 : h);
                const float rmk = ((unsigned)h < (unsigned)IH) ? 1.0f : 0.0f;
                pv[rr] = P[(size_t)hc * IW + wc] * rmk;
                tv[rr] = T[(size_t)hc * IW + wc] * rmk;
            }
        }
        // liveness anchor: all 36 loaded values must be simultaneously live
        // here -> RA cannot serialize the loads into load->wait->use chains.
        asm volatile("" ::
            "v"(pv[0]), "v"(pv[1]), "v"(pv[2]), "v"(pv[3]), "v"(pv[4]),
            "v"(pv[5]), "v"(pv[6]), "v"(pv[7]), "v"(pv[8]), "v"(pv[9]),
            "v"(pv[10]), "v"(pv[11]), "v"(pv[12]), "v"(pv[13]), "v"(pv[14]),
            "v"(pv[15]), "v"(pv[16]), "v"(pv[17]),
            "v"(tv[0]), "v"(tv[1]), "v"(tv[2]), "v"(tv[3]), "v"(tv[4]),
            "v"(tv[5]), "v"(tv[6]), "v"(tv[7]), "v"(tv[8]), "v"(tv[9]),
            "v"(tv[10]), "v"(tv[11]), "v"(tv[12]), "v"(tv[13]), "v"(tv[14]),
            "v"(tv[15]), "v"(tv[16]), "v"(tv[17]));
        __builtin_amdgcn_sched_barrier(0);

        f32x2 a01[TH], a23[TH];
        #pragma unroll
        for (int ro = 0; ro < TH; ++ro) {
            a01[ro] = (f32x2){0.f, 0.f};
            a23[ro] = (f32x2){0.f, 0.f};
        }

        #pragma unroll
        for (int rr = 0; rr < RRN; ++rr) {
            const float p = pv[rr], t = tv[rr];
            f32x2 s01; s01.x = p; s01.y = t;
            f32x2 s23;
            s23.x = fmaf(p, p, t * t);        // p^2 + t^2
            s23.y = p * t;                    // p*t
            #pragma unroll
            for (int ro = 0; ro < TH; ++ro) {
                const int k = rr - ro;        // static after unroll
                if (k >= 0 && k < 11) {
                    const f32x2 g = {GW[k], GW[k]};
                    a01[ro] = __builtin_elementwise_fma(g, s01, a01[ro]);
                    a23[ro] = __builtin_elementwise_fma(g, s23, a23[ro]);
                }
            }
        }
        const f32x2 wmv = {wm, wm};
        #pragma unroll
        for (int ro = 0; ro < TH; ++ro) {
            lds01[ro][tid] = a01[ro] * wmv;
            lds23[ro][tid] = a23[ro] * wmv;
        }
    }
    __syncthreads();

    // ---------------- H-phase: ALL 512 threads, one row-quad each ----------
    float lsum = 0.0f;
    {
        const int r  = tid >> 6;            // 0..7 (one row per wave)
        const int c0 = (tid & 63) << 2;     // 0..252 (f32x2 elements)

        float4 u4[7], v4[7];
        const float4* b01 = reinterpret_cast<const float4*>(&lds01[r][c0]);
        const float4* b23 = reinterpret_cast<const float4*>(&lds23[r][c0]);
        #pragma unroll
        for (int q = 0; q < 7; ++q) { u4[q] = b01[q]; v4[q] = b23[q]; }
        const f32x2* x01 = reinterpret_cast<const f32x2*>(u4);   // 14 elems
        const f32x2* x23 = reinterpret_cast<const f32x2*>(v4);

        #pragma unroll
        for (int j = 0; j < 4; ++j) {
            f32x2 acc01 = {0.f, 0.f};
            f32x2 acc23 = {0.f, 0.f};
            #pragma unroll
            for (int k = 0; k < 11; ++k) {
                const f32x2 g = {GW[k], GW[k]};
                acc01 = __builtin_elementwise_fma(g, x01[j + k], acc01);
                acc23 = __builtin_elementwise_fma(g, x23[j + k], acc23);
            }
            const float m1  = acc01.x;
            const float m2  = acc01.y;
            const float sPP = acc23.x;      // E[p^2]+E[t^2]
            const float e12 = acc23.y;      // E[p*t]
            const float m1m2 = m1 * m2;
            const float msq  = fmaf(m1, m1, m2 * m2);
            const float num = fmaf(2.0f, m1m2, C1f) * fmaf(2.0f, (e12 - m1m2), C2f);
            const float den = (msq + C1f) * ((sPP - msq) + C2f);
            lsum = fmaf(num, __builtin_amdgcn_rcpf(den), lsum);
        }
    }

    // ---------------- Reduction: wave shuffle -> LDS -> plain store --------
    #pragma unroll
    for (int off = 32; off > 0; off >>= 1) lsum += __shfl_down(lsum, off, 64);
    const int lane = tid & 63;
    const int wv   = tid >> 6;              // 0..7
    if (lane == 0) wsum[wv] = lsum;
    __syncthreads();
    if (tid == 0) {
        float bs = 0.f;
        #pragma unroll
        for (int i = 0; i < 8; ++i) bs += wsum[i];
        ws[b] = bs;
    }
}

extern "C" void kernel_launch(void* const* d_in, const int* in_sizes, int n_in,
                              void* d_out, int out_size, void* d_ws, size_t ws_size,
                              hipStream_t stream) {
    const float* pred = (const float*)d_in[0];
    const float* targ = (const float*)d_in[1];
    float* out = (float*)d_out;
    float* wsf = (float*)d_ws;               // needs 12288 floats = 48 KB

    hipLaunchKernelGGL(ssim_main, dim3(NBLK), dim3(NTHR), 0, stream,
                       pred, targ, wsf);
    hipLaunchKernelGGL(ssim_reduce, dim3(1), dim3(1024), 0, stream, wsf, out);
}